// Round 8
// baseline (14.692 us; speedup 1.0000x reference)
//
#include <hip/hip_runtime.h>
#include <math.h>

#define IEPS 1e-8f

typedef float f4 __attribute__((ext_vector_type(4)));
struct __attribute__((packed, aligned(4))) F4u { f4 v; };

__device__ __forceinline__ float fast_rcp(float x) { return __builtin_amdgcn_rcpf(x); }

// Clip p + t*d, t in [0,1], vs AABB [-hw,hw]x[-hh,hh]; rd = 1/d (precomputed).
// d==0 handled by IEEE inf/NaN semantics of v_min/v_max.
__device__ __forceinline__ float slab_dt(float px, float py, float rdx, float rdy,
                                         float hw, float hh)
{
    float ax = (-hw - px) * rdx, bx = (hw - px) * rdx;
    float ay = (-hh - py) * rdy, by = (hh - py) * rdy;
    float t0 = fmaxf(fmaxf(fminf(ax, bx), fminf(ay, by)), 0.0f);
    float t1 = fminf(fminf(fmaxf(ax, bx), fmaxf(ay, by)), 1.0f);
    return fmaxf(t1 - t0, 0.0f);
}

__global__ __launch_bounds__(256) void iou3d_partial_kernel(
    const float* __restrict__ pred,
    const float* __restrict__ target,
    const float* __restrict__ weight,
    float* __restrict__ partial,
    int N)
{
    const int t   = threadIdx.x;
    const int bid = blockIdx.x;
    const int i   = bid * 256 + t;

    float contrib = 0.0f;
    if (i < N) {
        const float* P = pred + (size_t)i * 7;
        const float* T = target + (size_t)i * 7;
        f4 pA = ((const F4u*)P)->v;          // x, y, z, w
        f4 pB = ((const F4u*)(P + 3))->v;    // w, h, dz, yaw
        f4 tA = ((const F4u*)T)->v;
        f4 tB = ((const F4u*)(T + 3))->v;
        float wgt = weight[i];

        // extract scalars; f4s die here
        float cx1 = pA[0], cy1 = pA[1], z1 = pA[2];
        float w1 = pA[3], h1 = pB[1], dz1 = pB[2], yaw1 = pB[3];
        float cx2 = tA[0], cy2 = tA[1], z2 = tA[2];
        float w2 = tA[3], h2 = tB[1], dz2 = tB[2], yaw2 = tB[3];

        float hw1 = 0.5f * w1, hh1 = 0.5f * h1;
        float hw2 = 0.5f * w2, hh2 = 0.5f * h2;
        float c1a = __cosf(yaw1), s1a = __sinf(yaw1);
        float c2a = __cosf(yaw2), s2a = __sinf(yaw2);

        // center offsets in each frame; relative rotation r = a2 - a1
        float dxg = cx2 - cx1, dyg = cy2 - cy1;
        float t12x =  dxg * c1a + dyg * s1a;     // box2 center in frame1
        float t12y = -dxg * s1a + dyg * c1a;
        float t21x = -(dxg * c2a + dyg * s2a);   // box1 center in frame2
        float t21y =  (dxg * s2a - dyg * c2a);
        float cr = c2a * c1a + s2a * s1a;
        float sr = s2a * c1a - c2a * s1a;

        // ---------- phase Q: box2's edges clipped by box1's AABB (frame1) ----------
        // fx = R(+r)(hw2,0), fy = R(+r)(0,hh2)
        float fxx =  hw2 * cr, fxy = hw2 * sr;
        float fyx = -hh2 * sr, fyy = hh2 * cr;
        float q0x = t12x - fxx - fyx, q0y = t12y - fxy - fyy;
        float q1x = t12x + fxx - fyx, q1y = t12y + fxy - fyy;
        float q2x = t12x + fxx + fyx, q2y = t12y + fxy + fyy;
        float q3x = t12x - fxx + fyx, q3y = t12y - fxy + fyy;
        float g0x = fxx + fxx, g0y = fxy + fxy;
        float g1x = fyx + fyx, g1y = fyy + fyy;
        float rg0x = fast_rcp(g0x), rg0y = fast_rcp(g0y);
        float rg1x = fast_rcp(g1x), rg1y = fast_rcp(g1y);

        float sdt = slab_dt(q0x, q0y,  rg0x,  rg0y, hw1, hh1)
                  + slab_dt(q1x, q1y,  rg1x,  rg1y, hw1, hh1)
                  + slab_dt(q2x, q2y, -rg0x, -rg0y, hw1, hh1)
                  + slab_dt(q3x, q3y, -rg1x, -rg1y, hw1, hh1);

        // pinch point: keep phase Q's registers from interleaving with phase P
        __builtin_amdgcn_sched_barrier(0);

        // ---------- phase P: box1's edges clipped by box2's AABB (frame2) ----------
        // ex = R(-r)(hw1,0), ey = R(-r)(0,hh1)
        float exx = hw1 * cr, exy = -hw1 * sr;
        float eyx = hh1 * sr, eyy =  hh1 * cr;
        float p0x = t21x - exx - eyx, p0y = t21y - exy - eyy;
        float p1x = t21x + exx - eyx, p1y = t21y + exy - eyy;
        float p2x = t21x + exx + eyx, p2y = t21y + exy + eyy;
        float p3x = t21x - exx + eyx, p3y = t21y - exy + eyy;
        float d0x = exx + exx, d0y = exy + exy;
        float d1x = eyx + eyx, d1y = eyy + eyy;
        float rd0x = fast_rcp(d0x), rd0y = fast_rcp(d0y);
        float rd1x = fast_rcp(d1x), rd1y = fast_rcp(d1y);

        float area2 = 2.0f * hw2 * hh2 * sdt;   // box2 edges: cross(p,d) const in frame2
        float dt;
        dt = slab_dt(p0x, p0y,  rd0x,  rd0y, hw2, hh2); area2 += dt * (p0x * d0y - p0y * d0x);
        dt = slab_dt(p1x, p1y,  rd1x,  rd1y, hw2, hh2); area2 += dt * (p1x * d1y - p1y * d1x);
        dt = slab_dt(p2x, p2y, -rd0x, -rd0y, hw2, hh2); area2 -= dt * (p2x * d0y - p2y * d0x);
        dt = slab_dt(p3x, p3y, -rd1x, -rd1y, hw2, hh2); area2 -= dt * (p3x * d1y - p3y * d1x);

        float inter2d = 0.5f * fabsf(area2);

        // z overlap + IoU
        float hz1 = 0.5f * dz1, hz2 = 0.5f * dz2;
        float zo = fmaxf(fminf(z1 + hz1, z2 + hz2) - fmaxf(z1 - hz1, z2 - hz2), 0.0f);
        float inter3d = inter2d * zo;
        float v1 = w1 * h1 * dz1;
        float v2 = w2 * h2 * dz2;
        float denom = fmaxf(v1 + v2 - inter3d, IEPS);
        contrib = wgt * (1.0f - inter3d / denom);
    }

    // wave(64) reduction; one partial per wave (no LDS, no barrier)
    #pragma unroll
    for (int off = 32; off > 0; off >>= 1)
        contrib += __shfl_down(contrib, off);

    if ((t & 63) == 0)
        partial[bid * 4 + (t >> 6)] = contrib;
}

__global__ __launch_bounds__(256) void iou3d_reduce_kernel(
    const float* __restrict__ partial, float* __restrict__ out,
    int nPart, float invN)
{
    int t = threadIdx.x;
    float s = 0.0f;
    for (int k = t; k < nPart; k += 256) s += partial[k];

    #pragma unroll
    for (int off = 32; off > 0; off >>= 1)
        s += __shfl_down(s, off);

    __shared__ float sm[4];
    if ((t & 63) == 0) sm[t >> 6] = s;
    __syncthreads();
    if (t == 0)
        out[0] = (sm[0] + sm[1] + sm[2] + sm[3]) * invN;
}

extern "C" void kernel_launch(void* const* d_in, const int* in_sizes, int n_in,
                              void* d_out, int out_size, void* d_ws, size_t ws_size,
                              hipStream_t stream) {
    const float* pred   = (const float*)d_in[0];
    const float* target = (const float*)d_in[1];
    const float* weight = (const float*)d_in[2];
    float* out = (float*)d_out;
    float* partial = (float*)d_ws;

    int N = in_sizes[0] / 7;
    float invN = 1.0f / (float)N;

    int block = 256;
    int grid = (N + block - 1) / block;   // 1024 for N=262144
    iou3d_partial_kernel<<<grid, block, 0, stream>>>(pred, target, weight, partial, N);
    iou3d_reduce_kernel<<<1, 256, 0, stream>>>(partial, out, grid * 4, invN);
}

// Round 9
// 14.327 us; speedup vs baseline: 1.0255x; 1.0255x over previous
//
#include <hip/hip_runtime.h>
#include <math.h>

#define IEPS 1e-8f

typedef float f4 __attribute__((ext_vector_type(4)));
struct __attribute__((packed, aligned(4))) F4u { f4 v; };

__device__ __forceinline__ float fast_rcp(float x) { return __builtin_amdgcn_rcpf(x); }

// Clip p + t*d, t in [0,1], vs AABB [-hw,hw]x[-hh,hh]; rd = 1/d (precomputed).
// d==0 handled by IEEE inf/NaN semantics of v_min/v_max.
__device__ __forceinline__ float slab_dt(float px, float py, float rdx, float rdy,
                                         float hw, float hh)
{
    float ax = (-hw - px) * rdx, bx = (hw - px) * rdx;
    float ay = (-hh - py) * rdy, by = (hh - py) * rdy;
    float t0 = fmaxf(fmaxf(fminf(ax, bx), fminf(ay, by)), 0.0f);
    float t1 = fminf(fminf(fmaxf(ax, bx), fmaxf(ay, by)), 1.0f);
    return fmaxf(t1 - t0, 0.0f);
}

__global__ __launch_bounds__(256) void iou3d_partial_kernel(
    const float* __restrict__ pred,
    const float* __restrict__ target,
    const float* __restrict__ weight,
    float* __restrict__ partial,
    int N)
{
    const int t   = threadIdx.x;
    const int bid = blockIdx.x;
    const int i   = bid * 256 + t;

    float contrib = 0.0f;
    if (i < N) {
        const float* P = pred + (size_t)i * 7;
        const float* T = target + (size_t)i * 7;
        f4 pA = ((const F4u*)P)->v;          // x, y, z, w
        f4 pB = ((const F4u*)(P + 3))->v;    // w, h, dz, yaw
        f4 tA = ((const F4u*)T)->v;
        f4 tB = ((const F4u*)(T + 3))->v;
        float wgt = weight[i];

        float cx1 = pA[0], cy1 = pA[1], z1 = pA[2];
        float w1 = pA[3], h1 = pB[1], dz1 = pB[2], yaw1 = pB[3];
        float cx2 = tA[0], cy2 = tA[1], z2 = tA[2];
        float w2 = tA[3], h2 = tB[1], dz2 = tB[2], yaw2 = tB[3];

        float hw1 = 0.5f * w1, hh1 = 0.5f * h1;
        float hw2 = 0.5f * w2, hh2 = 0.5f * h2;
        float c1a = __cosf(yaw1), s1a = __sinf(yaw1);
        float c2a = __cosf(yaw2), s2a = __sinf(yaw2);

        // center offsets in each frame; relative rotation r = a2 - a1
        float dxg = cx2 - cx1, dyg = cy2 - cy1;
        float t12x =  dxg * c1a + dyg * s1a;     // box2 center in frame1
        float t12y = -dxg * s1a + dyg * c1a;
        float t21x = -(dxg * c2a + dyg * s2a);   // box1 center in frame2
        float t21y =  (dxg * s2a - dyg * c2a);
        float cr = c2a * c1a + s2a * s1a;
        float sr = s2a * c1a - c2a * s1a;

        // ---- phase Q: box2's edges clipped by box1's AABB (frame1) ----
        // fx = R(+r)(hw2,0), fy = R(+r)(0,hh2)
        float fxx =  hw2 * cr, fxy = hw2 * sr;
        float fyx = -hh2 * sr, fyy = hh2 * cr;
        float q0x = t12x - fxx - fyx, q0y = t12y - fxy - fyy;
        float q1x = t12x + fxx - fyx, q1y = t12y + fxy - fyy;
        float q2x = t12x + fxx + fyx, q2y = t12y + fxy + fyy;
        float q3x = t12x - fxx + fyx, q3y = t12y - fxy + fyy;
        float g0x = fxx + fxx, g0y = fxy + fxy;
        float g1x = fyx + fyx, g1y = fyy + fyy;
        float rg0x = fast_rcp(g0x), rg0y = fast_rcp(g0y);
        float rg1x = fast_rcp(g1x), rg1y = fast_rcp(g1y);

        float sdt = slab_dt(q0x, q0y,  rg0x,  rg0y, hw1, hh1)
                  + slab_dt(q1x, q1y,  rg1x,  rg1y, hw1, hh1)
                  + slab_dt(q2x, q2y, -rg0x, -rg0y, hw1, hh1)
                  + slab_dt(q3x, q3y, -rg1x, -rg1y, hw1, hh1);

        // ---- phase P: box1's edges clipped by box2's AABB (frame2) ----
        // ex = R(-r)(hw1,0), ey = R(-r)(0,hh1)
        float exx = hw1 * cr, exy = -hw1 * sr;
        float eyx = hh1 * sr, eyy =  hh1 * cr;
        float p0x = t21x - exx - eyx, p0y = t21y - exy - eyy;
        float p1x = t21x + exx - eyx, p1y = t21y + exy - eyy;
        float p2x = t21x + exx + eyx, p2y = t21y + exy + eyy;
        float p3x = t21x - exx + eyx, p3y = t21y - exy + eyy;
        float d0x = exx + exx, d0y = exy + exy;
        float d1x = eyx + eyx, d1y = eyy + eyy;
        float rd0x = fast_rcp(d0x), rd0y = fast_rcp(d0y);
        float rd1x = fast_rcp(d1x), rd1y = fast_rcp(d1y);

        float area2 = 2.0f * hw2 * hh2 * sdt;   // box2 edges: cross(p,d) const in frame2
        float dt;
        dt = slab_dt(p0x, p0y,  rd0x,  rd0y, hw2, hh2); area2 += dt * (p0x * d0y - p0y * d0x);
        dt = slab_dt(p1x, p1y,  rd1x,  rd1y, hw2, hh2); area2 += dt * (p1x * d1y - p1y * d1x);
        dt = slab_dt(p2x, p2y, -rd0x, -rd0y, hw2, hh2); area2 -= dt * (p2x * d0y - p2y * d0x);
        dt = slab_dt(p3x, p3y, -rd1x, -rd1y, hw2, hh2); area2 -= dt * (p3x * d1y - p3y * d1x);

        float inter2d = 0.5f * fabsf(area2);

        // z overlap + IoU
        float hz1 = 0.5f * dz1, hz2 = 0.5f * dz2;
        float zo = fmaxf(fminf(z1 + hz1, z2 + hz2) - fmaxf(z1 - hz1, z2 - hz2), 0.0f);
        float inter3d = inter2d * zo;
        float v1 = w1 * h1 * dz1;
        float v2 = w2 * h2 * dz2;
        float denom = fmaxf(v1 + v2 - inter3d, IEPS);
        contrib = wgt * (1.0f - inter3d / denom);
    }

    // wave(64) reduction; one partial per wave (no LDS, no barrier)
    #pragma unroll
    for (int off = 32; off > 0; off >>= 1)
        contrib += __shfl_down(contrib, off);

    if ((t & 63) == 0)
        partial[bid * 4 + (t >> 6)] = contrib;
}

__global__ __launch_bounds__(256) void iou3d_reduce_kernel(
    const float* __restrict__ partial, float* __restrict__ out,
    int nPart, float invN)
{
    int t = threadIdx.x;
    float s = 0.0f;
    for (int k = t; k < nPart; k += 256) s += partial[k];

    #pragma unroll
    for (int off = 32; off > 0; off >>= 1)
        s += __shfl_down(s, off);

    __shared__ float sm[4];
    if ((t & 63) == 0) sm[t >> 6] = s;
    __syncthreads();
    if (t == 0)
        out[0] = (sm[0] + sm[1] + sm[2] + sm[3]) * invN;
}

extern "C" void kernel_launch(void* const* d_in, const int* in_sizes, int n_in,
                              void* d_out, int out_size, void* d_ws, size_t ws_size,
                              hipStream_t stream) {
    const float* pred   = (const float*)d_in[0];
    const float* target = (const float*)d_in[1];
    const float* weight = (const float*)d_in[2];
    float* out = (float*)d_out;
    float* partial = (float*)d_ws;

    int N = in_sizes[0] / 7;
    float invN = 1.0f / (float)N;

    int block = 256;
    int grid = (N + block - 1) / block;   // 1024 for N=262144
    iou3d_partial_kernel<<<grid, block, 0, stream>>>(pred, target, weight, partial, N);
    iou3d_reduce_kernel<<<1, 256, 0, stream>>>(partial, out, grid * 4, invN);
}

// Round 10
// 11.030 us; speedup vs baseline: 1.3320x; 1.2989x over previous
//
#include <hip/hip_runtime.h>
#include <math.h>

#define IEPS 1e-8f

typedef float f4 __attribute__((ext_vector_type(4)));
struct __attribute__((packed, aligned(4))) F4u { f4 v; };

__device__ __forceinline__ float fast_rcp(float x) { return __builtin_amdgcn_rcpf(x); }

// Clip p + t*d, t in [0,1], vs AABB [-hw,hw]x[-hh,hh]; rd = 1/d (precomputed).
// d==0 handled by IEEE inf/NaN semantics of v_min/v_max.
__device__ __forceinline__ float slab_dt(float px, float py, float rdx, float rdy,
                                         float hw, float hh)
{
    float ax = (-hw - px) * rdx, bx = (hw - px) * rdx;
    float ay = (-hh - py) * rdy, by = (hh - py) * rdy;
    float t0 = fmaxf(fmaxf(fminf(ax, bx), fminf(ay, by)), 0.0f);
    float t1 = fminf(fminf(fmaxf(ax, bx), fmaxf(ay, by)), 1.0f);
    return fmaxf(t1 - t0, 0.0f);
}

__global__ __launch_bounds__(256) void iou3d_partial_kernel(
    const float* __restrict__ pred,
    const float* __restrict__ target,
    const float* __restrict__ weight,
    float* __restrict__ partial,
    int N)
{
    const int t   = threadIdx.x;
    const int bid = blockIdx.x;
    const int i   = bid * 256 + t;

    float contrib = 0.0f;
    if (i < N) {
        const float* P = pred + (size_t)i * 7;
        const float* T = target + (size_t)i * 7;
        f4 pA = ((const F4u*)P)->v;          // x, y, z, w
        f4 pB = ((const F4u*)(P + 3))->v;    // w, h, dz, yaw
        f4 tA = ((const F4u*)T)->v;
        f4 tB = ((const F4u*)(T + 3))->v;
        float wgt = weight[i];

        float cx1 = pA[0], cy1 = pA[1], z1 = pA[2];
        float w1 = pA[3], h1 = pB[1], dz1 = pB[2], yaw1 = pB[3];
        float cx2 = tA[0], cy2 = tA[1], z2 = tA[2];
        float w2 = tA[3], h2 = tB[1], dz2 = tB[2], yaw2 = tB[3];

        float hw1 = 0.5f * w1, hh1 = 0.5f * h1;
        float hw2 = 0.5f * w2, hh2 = 0.5f * h2;
        float c1a = __cosf(yaw1), s1a = __sinf(yaw1);
        float c2a = __cosf(yaw2), s2a = __sinf(yaw2);

        // center offsets in each frame; relative rotation r = a2 - a1
        float dxg = cx2 - cx1, dyg = cy2 - cy1;
        float t12x =  dxg * c1a + dyg * s1a;     // box2 center in frame1
        float t12y = -dxg * s1a + dyg * c1a;
        float t21x = -(dxg * c2a + dyg * s2a);   // box1 center in frame2
        float t21y =  (dxg * s2a - dyg * c2a);
        float cr = c2a * c1a + s2a * s1a;
        float sr = s2a * c1a - c2a * s1a;

        // ---- box2's edges clipped by box1's AABB (frame1) ----
        float fxx =  hw2 * cr, fxy = hw2 * sr;
        float fyx = -hh2 * sr, fyy = hh2 * cr;
        float q0x = t12x - fxx - fyx, q0y = t12y - fxy - fyy;
        float q1x = t12x + fxx - fyx, q1y = t12y + fxy - fyy;
        float q2x = t12x + fxx + fyx, q2y = t12y + fxy + fyy;
        float q3x = t12x - fxx + fyx, q3y = t12y - fxy + fyy;
        float g0x = fxx + fxx, g0y = fxy + fxy;
        float g1x = fyx + fyx, g1y = fyy + fyy;
        float rg0x = fast_rcp(g0x), rg0y = fast_rcp(g0y);
        float rg1x = fast_rcp(g1x), rg1y = fast_rcp(g1y);

        float sdt = slab_dt(q0x, q0y,  rg0x,  rg0y, hw1, hh1)
                  + slab_dt(q1x, q1y,  rg1x,  rg1y, hw1, hh1)
                  + slab_dt(q2x, q2y, -rg0x, -rg0y, hw1, hh1)
                  + slab_dt(q3x, q3y, -rg1x, -rg1y, hw1, hh1);

        // ---- box1's edges clipped by box2's AABB (frame2) ----
        float exx = hw1 * cr, exy = -hw1 * sr;
        float eyx = hh1 * sr, eyy =  hh1 * cr;
        float p0x = t21x - exx - eyx, p0y = t21y - exy - eyy;
        float p1x = t21x + exx - eyx, p1y = t21y + exy - eyy;
        float p2x = t21x + exx + eyx, p2y = t21y + exy + eyy;
        float p3x = t21x - exx + eyx, p3y = t21y - exy + eyy;
        float d0x = exx + exx, d0y = exy + exy;
        float d1x = eyx + eyx, d1y = eyy + eyy;
        float rd0x = fast_rcp(d0x), rd0y = fast_rcp(d0y);
        float rd1x = fast_rcp(d1x), rd1y = fast_rcp(d1y);

        float area2 = 2.0f * hw2 * hh2 * sdt;   // box2 edges: cross(p,d) const in frame2
        float dt;
        dt = slab_dt(p0x, p0y,  rd0x,  rd0y, hw2, hh2); area2 += dt * (p0x * d0y - p0y * d0x);
        dt = slab_dt(p1x, p1y,  rd1x,  rd1y, hw2, hh2); area2 += dt * (p1x * d1y - p1y * d1x);
        dt = slab_dt(p2x, p2y, -rd0x, -rd0y, hw2, hh2); area2 -= dt * (p2x * d0y - p2y * d0x);
        dt = slab_dt(p3x, p3y, -rd1x, -rd1y, hw2, hh2); area2 -= dt * (p3x * d1y - p3y * d1x);

        float inter2d = 0.5f * fabsf(area2);

        // z overlap + IoU
        float hz1 = 0.5f * dz1, hz2 = 0.5f * dz2;
        float zo = fmaxf(fminf(z1 + hz1, z2 + hz2) - fmaxf(z1 - hz1, z2 - hz2), 0.0f);
        float inter3d = inter2d * zo;
        float v1 = w1 * h1 * dz1;
        float v2 = w2 * h2 * dz2;
        float denom = fmaxf(v1 + v2 - inter3d, IEPS);
        contrib = wgt * (1.0f - inter3d / denom);
    }

    // R4's reduction: wave shuffle + LDS block reduce, one partial per block
    #pragma unroll
    for (int off = 32; off > 0; off >>= 1)
        contrib += __shfl_down(contrib, off);

    __shared__ float sred[4];
    int lane = t & 63;
    int wid  = t >> 6;
    if (lane == 0) sred[wid] = contrib;
    __syncthreads();
    if (t == 0)
        partial[bid] = sred[0] + sred[1] + sred[2] + sred[3];
}

__global__ __launch_bounds__(1024) void iou3d_reduce_kernel(
    const float* __restrict__ partial, float* __restrict__ out,
    int nPart, float invN)
{
    int t = threadIdx.x;
    float s = 0.0f;
    for (int k = t; k < nPart; k += 1024) s += partial[k];

    #pragma unroll
    for (int off = 32; off > 0; off >>= 1)
        s += __shfl_down(s, off);

    __shared__ float sm[16];
    if ((t & 63) == 0) sm[t >> 6] = s;
    __syncthreads();
    if (t == 0) {
        float tot = 0.0f;
        #pragma unroll
        for (int k = 0; k < 16; ++k) tot += sm[k];
        out[0] = tot * invN;
    }
}

extern "C" void kernel_launch(void* const* d_in, const int* in_sizes, int n_in,
                              void* d_out, int out_size, void* d_ws, size_t ws_size,
                              hipStream_t stream) {
    const float* pred   = (const float*)d_in[0];
    const float* target = (const float*)d_in[1];
    const float* weight = (const float*)d_in[2];
    float* out = (float*)d_out;
    float* partial = (float*)d_ws;

    int N = in_sizes[0] / 7;
    float invN = 1.0f / (float)N;

    int block = 256;
    int grid = (N + block - 1) / block;   // 1024 for N=262144
    iou3d_partial_kernel<<<grid, block, 0, stream>>>(pred, target, weight, partial, N);
    iou3d_reduce_kernel<<<1, 1024, 0, stream>>>(partial, out, grid, invN);
}